// Round 13
// baseline (103.637 us; speedup 1.0000x reference)
//
#include <hip/hip_runtime.h>
#include <hip/hip_bf16.h>
#include <stdint.h>

#define NN    4096
#define INF_  256
#define HEADS 4
#define HID   64
#define OUTC  256
#define NEG   0.2f
#define L2E   1.44269504f

#define BI     64               // i-rows per block (16 per wave)
#define JSPLIT 8
#define NJ     (NN / JSPLIT)

typedef short bf16x8 __attribute__((ext_vector_type(8)));
typedef float f32x4  __attribute__((ext_vector_type(4)));

// ---- float <-> order-preserving uint encoding (for atomicMax on f32) ----
__device__ __forceinline__ uint32_t ford(float x){
  uint32_t u = __float_as_uint(x);
  return (u & 0x80000000u) ? ~u : (u | 0x80000000u);
}
__device__ __forceinline__ float funord(uint32_t e){
  uint32_t u = (e & 0x80000000u) ? (e & 0x7fffffffu) : ~e;
  return __uint_as_float(u);
}
__device__ __forceinline__ ushort bf16u(float f){
  __hip_bfloat16 b = __float2bfloat16(f);
  return *reinterpret_cast<ushort*>(&b);
}

// ---- adjacency int32 [4096][4096] -> bitmask bytes (proven r11) ----
__launch_bounds__(256)
__global__ void k_pack(const int* __restrict__ adj, ushort* __restrict__ bmb){
  int row = blockIdx.x;
  int t   = threadIdx.x;
  const int* p = adj + (size_t)row*NN + t*16;
  int4 v0 = *(const int4*)(p);
  int4 v1 = *(const int4*)(p + 4);
  int4 v2 = *(const int4*)(p + 8);
  int4 v3 = *(const int4*)(p + 12);
  uint32_t b = 0;
  b |= (v0.x ? 0x0001u : 0u); b |= (v0.y ? 0x0002u : 0u);
  b |= (v0.z ? 0x0004u : 0u); b |= (v0.w ? 0x0008u : 0u);
  b |= (v1.x ? 0x0010u : 0u); b |= (v1.y ? 0x0020u : 0u);
  b |= (v1.z ? 0x0040u : 0u); b |= (v1.w ? 0x0080u : 0u);
  b |= (v2.x ? 0x0100u : 0u); b |= (v2.y ? 0x0200u : 0u);
  b |= (v2.z ? 0x0400u : 0u); b |= (v2.w ? 0x0800u : 0u);
  b |= (v3.x ? 0x1000u : 0u); b |= (v3.y ? 0x2000u : 0u);
  b |= (v3.z ? 0x4000u : 0u); b |= (v3.w ? 0x8000u : 0u);
  bmb[(size_t)row*256 + t] = (ushort)b;
}

// ---- g = h @ W^T per head-tile (f32 VALU, proven); emits gT (bf16,
//      [c][j] transposed), slT2/srT2 (log2e-scaled) and per-head srmax ----
__launch_bounds__(256)
__global__ void k_gemm(const float* __restrict__ hmat, const float* __restrict__ W,
                       const float* __restrict__ aw,
                       short* __restrict__ gT, float* __restrict__ slT2,
                       float* __restrict__ srT2, uint32_t* __restrict__ srmax2){
  __shared__ float hsT[64][68];   // [k][row]
  __shared__ float wsT[64][68];   // [k][col]
  __shared__ float smax_l[16];
  int t  = threadIdx.x;
  int tx = t & 15, ty = t >> 4;
  int r0 = blockIdx.x * 64;
  int cb = blockIdx.y;            // head
  int c0 = cb * 64;
  float acc[4][4] = {};

  for (int k0 = 0; k0 < INF_; k0 += 64){
    int row = t >> 2, kc = (t & 3) * 16;   // transpose-on-load (h tile)
    #pragma unroll
    for (int u = 0; u < 4; u++){
      float4 v = *(const float4*)&hmat[(r0 + row)*INF_ + k0 + kc + 4*u];
      hsT[kc + 4*u + 0][row] = v.x;
      hsT[kc + 4*u + 1][row] = v.y;
      hsT[kc + 4*u + 2][row] = v.z;
      hsT[kc + 4*u + 3][row] = v.w;
    }
    #pragma unroll
    for (int u = 0; u < 4; u++){            // W[c][k] -> wsT[k][c]
      float4 v = *(const float4*)&W[(c0 + row)*INF_ + k0 + kc + 4*u];
      wsT[kc + 4*u + 0][row] = v.x;
      wsT[kc + 4*u + 1][row] = v.y;
      wsT[kc + 4*u + 2][row] = v.z;
      wsT[kc + 4*u + 3][row] = v.w;
    }
    __syncthreads();
    #pragma unroll 8
    for (int k = 0; k < 64; k++){
      float4 hv = *(const float4*)&hsT[k][ty*4];
      float4 wv = *(const float4*)&wsT[k][tx*4];
      float ha[4] = {hv.x, hv.y, hv.z, hv.w};
      float wa[4] = {wv.x, wv.y, wv.z, wv.w};
      #pragma unroll
      for (int a_ = 0; a_ < 4; a_++)
        #pragma unroll
        for (int b_ = 0; b_ < 4; b_++)
          acc[a_][b_] = fmaf(ha[a_], wa[b_], acc[a_][b_]);
    }
    __syncthreads();
  }

  // scores (log2e-scaled)
  float alv[4], arv[4];
  #pragma unroll
  for (int j = 0; j < 4; j++){ alv[j] = aw[tx*4 + j]; arv[j] = aw[64 + tx*4 + j]; }
  float rmax = -3.4e38f;
  #pragma unroll
  for (int qi = 0; qi < 4; qi++){
    int r = r0 + ty*4 + qi;
    float slp = 0.f, srp = 0.f;
    #pragma unroll
    for (int j = 0; j < 4; j++){
      slp = fmaf(acc[qi][j], alv[j], slp);
      srp = fmaf(acc[qi][j], arv[j], srp);
    }
    #pragma unroll
    for (int m = 1; m < 16; m <<= 1){
      slp += __shfl_xor(slp, m, 64);
      srp += __shfl_xor(srp, m, 64);
    }
    if (tx == 0){
      slT2[(size_t)cb*NN + r] = slp * L2E;
      srT2[(size_t)cb*NN + r] = srp * L2E;
      rmax = fmaxf(rmax, srp * L2E);
    }
  }
  if (tx == 0) smax_l[ty] = rmax;

  // transpose acc -> gT (bf16) via LDS reuse
  float* T = (float*)hsT;                    // [c][r] stride 65
  #pragma unroll
  for (int qi = 0; qi < 4; qi++)
    #pragma unroll
    for (int j = 0; j < 4; j++)
      T[(tx*4 + j)*65 + ty*4 + qi] = acc[qi][j];
  __syncthreads();
  if (t == 0){
    float m = smax_l[0];
    #pragma unroll
    for (int i = 1; i < 16; i++) m = fmaxf(m, smax_l[i]);
    atomicMax(srmax2 + cb, ford(m));
  }
  int c = t >> 2, rb = (t & 3) * 16;
  ushort u16[16];
  #pragma unroll
  for (int v = 0; v < 16; v++) u16[v] = bf16u(T[c*65 + rb + v]);
  *(uint4*)&gT[(size_t)(c0 + c)*NN + r0 + rb]     = *(uint4*)&u16[0];
  *(uint4*)&gT[(size_t)(c0 + c)*NN + r0 + rb + 8] = *(uint4*)&u16[8];
}

// ---- fused masked-softmax attention: ONE head per block, 4 waves = 4 i-subtiles
//      (16 rows each). Same proven per-wave step as r11 (reg-dbuf B, LDS-staged
//      bm+sr prefetched a step ahead, den via ones-MFMA, sign-extend masking).
//      2048 blocks; 4 waves/block share identical B fragments -> L1 reuse. ----
__launch_bounds__(256, 4)
__global__ void k_attn(const short* __restrict__ gT, const float* __restrict__ slT2,
                       const float* __restrict__ srT2, const uint32_t* __restrict__ srmax2,
                       const uint32_t* __restrict__ bm,
                       __hip_bfloat16* __restrict__ num_p, float* __restrict__ den_p){
  __shared__ uint32_t bmlds[64 * 20];   // [row][word] stride 20 -> 16B-aligned, 2-way max
  __shared__ float    srs[512];         // this head's sr slice, log2e-scaled
  int t  = threadIdx.x;
  int w  = t >> 6, l = t & 63;
  int lr = l & 15, lg = l >> 4;
  int h  = blockIdx.y;
  int ib = blockIdx.x * BI;             // block's first i-row
  int i0 = ib + w*16;                   // wave's first i-row
  int jb = blockIdx.z * NJ;
  int js = blockIdx.z;

  // stage sr slice (512 floats) + bitmask tile (64 rows x 16 words)
  if (t < 128)
    *(float4*)&srs[t*4] = *(const float4*)&srT2[(size_t)h*NN + jb + t*4];
  {
    int r = t >> 2, wd = (t & 3) * 4;
    uint4 v = *(const uint4*)&bm[(size_t)(ib + r)*128 + (jb >> 5) + wd];
    *(uint4*)&bmlds[r*20 + wd] = v;
  }

  float srmaxh = funord(srmax2[h]);
  float slv = slT2[(size_t)h*NN + i0 + lr];
  float xx  = slv + srmaxh;
  float msh = fmaxf(xx, NEG * xx);
  float d1  = slv - msh;              // z = d1 + sr
  float cc  = (NEG - 1.0f) * msh;     // neg branch: NEG*z + cc
  __syncthreads();

  f32x4 acc[4] = {};
  f32x4 dacc   = {};
  bf16x8 ones;
  #pragma unroll
  for (int q = 0; q < 8; q++) ones[q] = (short)0x3F80;

  const short* gTh = gT + (size_t)h*HID*NN;
  const short* bp[4];
  #pragma unroll
  for (int n = 0; n < 4; n++)
    bp[n] = gTh + (size_t)(n*16 + lr)*NN + jb + lg*8;

  bf16x8 Bb[2][4];
  #pragma unroll
  for (int n = 0; n < 4; n++){
    Bb[0][n] = *(const bf16x8*)(bp[n]);
    Bb[1][n] = *(const bf16x8*)(bp[n] + 32);
  }

  // step-0 LDS operands
  int rowl = w*16 + lr;
  float4 s0c = *(const float4*)&srs[lg*8];
  float4 s1c = *(const float4*)&srs[lg*8 + 4];
  uint32_t w0c = bmlds[rowl*20];

  #pragma unroll
  for (int s = 0; s < 16; s++){
    // prefetch next step's LDS operands
    float4 s0n = s0c, s1n = s1c;
    uint32_t w0n = 0;
    if (s < 15){
      s0n = *(const float4*)&srs[(s+1)*32 + lg*8];
      s1n = *(const float4*)&srs[(s+1)*32 + lg*8 + 4];
      w0n = bmlds[rowl*20 + s + 1];
    }
    float sr8[8] = {s0c.x, s0c.y, s0c.z, s0c.w, s1c.x, s1c.y, s1c.z, s1c.w};

    uint32_t word = w0c >> (lg*8);
    uint32_t pk[4];
    #pragma unroll
    for (int p = 0; p < 4; p++){
      float z0 = d1 + sr8[2*p];
      float z1 = d1 + sr8[2*p + 1];
      float v0 = __builtin_amdgcn_exp2f(fmaxf(z0, fmaf(NEG, z0, cc)));
      float v1 = __builtin_amdgcn_exp2f(fmaxf(z1, fmaf(NEG, z1, cc)));
      int m0 = (int)(word << (31 - 2*p)) >> 31;     // bit 2p   -> all-ones/zero
      int m1 = (int)(word << (30 - 2*p)) >> 31;     // bit 2p+1
      v0 = __uint_as_float(__float_as_uint(v0) & (uint32_t)m0);
      v1 = __uint_as_float(__float_as_uint(v1) & (uint32_t)m1);
      pk[p] = ((__float_as_uint(v0) + 0x8000u) >> 16) |
              ((__float_as_uint(v1) + 0x8000u) & 0xffff0000u);
    }
    bf16x8 A = *(bf16x8*)pk;

    __builtin_amdgcn_s_setprio(1);
    dacc = __builtin_amdgcn_mfma_f32_16x16x32_bf16(A, ones, dacc, 0, 0, 0);
    #pragma unroll
    for (int n = 0; n < 4; n++)
      acc[n] = __builtin_amdgcn_mfma_f32_16x16x32_bf16(A, Bb[s & 1][n], acc[n], 0, 0, 0);
    __builtin_amdgcn_s_setprio(0);

    if (s + 2 < 16){
      #pragma unroll
      for (int n = 0; n < 4; n++)
        Bb[s & 1][n] = *(const bf16x8*)(bp[n] + (s + 2)*32);
    }
    s0c = s0n; s1c = s1n; w0c = w0n;
  }

  // num partials (bf16): row = i0+lg*4+r, col = h*64+n*16+lr
  #pragma unroll
  for (int n = 0; n < 4; n++)
    #pragma unroll
    for (int r = 0; r < 4; r++)
      num_p[((size_t)js*NN + i0 + lg*4 + r)*OUTC + h*HID + n*16 + lr] =
          __float2bfloat16(acc[n][r]);

  // den partials from ones-MFMA: row i0+lg*4+r value sits in dacc[r] (any lr)
  if (lr == 0)
    #pragma unroll
    for (int r = 0; r < 4; r++)
      den_p[((size_t)js*4 + h)*NN + i0 + lg*4 + r] = dacc[r];
}

// ---- combine partials: out = sum(num)/sum(den), 2 cols/thread ----
__global__ void k_comb(const __hip_bfloat16* __restrict__ num_p,
                       const float* __restrict__ den_p, float* __restrict__ out){
  int t  = threadIdx.x;
  int r  = blockIdx.x*2 + (t >> 7);
  int c2 = (t & 127) * 2;
  int h  = c2 >> 6;
  float s0 = 0.f, s1 = 0.f, d = 0.f;
  #pragma unroll
  for (int js = 0; js < JSPLIT; js++){
    uint32_t u = *(const uint32_t*)&num_p[((size_t)js*NN + r)*OUTC + c2];
    s0 += __uint_as_float(u << 16);
    s1 += __uint_as_float(u & 0xffff0000u);
  }
  #pragma unroll
  for (int js = 0; js < JSPLIT; js++)
    d += den_p[((size_t)js*4 + h)*NN + r];
  float inv = 1.0f / d;
  *(float2*)&out[(size_t)r*OUTC + c2] = make_float2(s0*inv, s1*inv);
}

extern "C" void kernel_launch(void* const* d_in, const int* in_sizes, int n_in,
                              void* d_out, int out_size, void* d_ws, size_t ws_size,
                              hipStream_t stream){
  const float* hmat = (const float*)d_in[0];
  const int*   adj  = (const int*)d_in[1];     // int32 layout confirmed in r1
  const float* W    = (const float*)d_in[2];
  const float* aw   = (const float*)d_in[3];
  float* out = (float*)d_out;
  char*  ws  = (char*)d_ws;

  // ws layout (bytes), total ~21.6 MB
  uint32_t* srmax2 = (uint32_t*)(ws);                      // 64 B
  float*    slT2   = (float*)(ws + 1024);                  // 64 KB
  float*    srT2   = (float*)(ws + 66560);                 // 64 KB
  short*    gT     = (short*)(ws + 132096);                // 2 MB   [256][4096] bf16
  float*    den_p  = (float*)(ws + 2229248);               // 512 KB [8][4][4096]
  __hip_bfloat16* num_p = (__hip_bfloat16*)(ws + 2753536); // 16.75 MB [8][4096][256]
  uint32_t* bmask  = (uint32_t*)(ws + 19530752);           // 2 MB   [4096][128] (byte-packed)

  hipMemsetAsync(ws, 0, 64, stream);   // srmax2 init
  hipLaunchKernelGGL(k_pack, dim3(NN), dim3(256), 0, stream, adj, (ushort*)bmask);
  hipLaunchKernelGGL(k_gemm, dim3(64, 4), dim3(256), 0, stream,
                     hmat, W, aw, gT, slT2, srT2, srmax2);
  hipLaunchKernelGGL(k_attn, dim3(NN/BI, HEADS, JSPLIT), dim3(256), 0, stream,
                     gT, slT2, srT2, srmax2, bmask, num_p, den_p);
  hipLaunchKernelGGL(k_comb, dim3(NN/2), dim3(256), 0, stream, num_p, den_p, out);
}

// Round 14
// 78.174 us; speedup vs baseline: 1.3257x; 1.3257x over previous
//
#include <hip/hip_runtime.h>
#include <hip/hip_bf16.h>
#include <stdint.h>

#define NN    4096
#define INF_  256
#define HEADS 4
#define HID   64
#define OUTC  256
#define NEG   0.2f
#define L2E   1.44269504f

#define BI     32
#define JSPLIT 8
#define NJ     (NN / JSPLIT)

typedef short bf16x8 __attribute__((ext_vector_type(8)));
typedef float f32x4  __attribute__((ext_vector_type(4)));

// ---- float <-> order-preserving uint encoding (for atomicMax on f32) ----
__device__ __forceinline__ uint32_t ford(float x){
  uint32_t u = __float_as_uint(x);
  return (u & 0x80000000u) ? ~u : (u | 0x80000000u);
}
__device__ __forceinline__ float funord(uint32_t e){
  uint32_t u = (e & 0x80000000u) ? (e & 0x7fffffffu) : ~e;
  return __uint_as_float(u);
}
__device__ __forceinline__ ushort bf16u(float f){
  __hip_bfloat16 b = __float2bfloat16(f);
  return *reinterpret_cast<ushort*>(&b);
}

__device__ __forceinline__ uint32_t pack16(int4 v0, int4 v1, int4 v2, int4 v3){
  uint32_t b = 0;
  b |= (v0.x ? 0x0001u : 0u); b |= (v0.y ? 0x0002u : 0u);
  b |= (v0.z ? 0x0004u : 0u); b |= (v0.w ? 0x0008u : 0u);
  b |= (v1.x ? 0x0010u : 0u); b |= (v1.y ? 0x0020u : 0u);
  b |= (v1.z ? 0x0040u : 0u); b |= (v1.w ? 0x0080u : 0u);
  b |= (v2.x ? 0x0100u : 0u); b |= (v2.y ? 0x0200u : 0u);
  b |= (v2.z ? 0x0400u : 0u); b |= (v2.w ? 0x0800u : 0u);
  b |= (v3.x ? 0x1000u : 0u); b |= (v3.y ? 0x2000u : 0u);
  b |= (v3.z ? 0x4000u : 0u); b |= (v3.w ? 0x8000u : 0u);
  return b;
}

// ---- adjacency int32 [4096][4096] -> bitmask bytes; 2 rows/block, 8 int4
//      loads in flight per thread before any compare (MLP=8) ----
__launch_bounds__(256)
__global__ void k_pack(const int* __restrict__ adj, ushort* __restrict__ bmb){
  int row = blockIdx.x * 2;
  int t   = threadIdx.x;
  const int* p0 = adj + (size_t)row*NN + t*16;
  const int* p1 = p0 + NN;
  int4 a0 = *(const int4*)(p0);      int4 a1 = *(const int4*)(p0 + 4);
  int4 a2 = *(const int4*)(p0 + 8);  int4 a3 = *(const int4*)(p0 + 12);
  int4 b0 = *(const int4*)(p1);      int4 b1 = *(const int4*)(p1 + 4);
  int4 b2 = *(const int4*)(p1 + 8);  int4 b3 = *(const int4*)(p1 + 12);
  bmb[(size_t)row*256 + t]       = (ushort)pack16(a0, a1, a2, a3);
  bmb[(size_t)(row + 1)*256 + t] = (ushort)pack16(b0, b1, b2, b3);
}

// ---- g = h @ W^T per head-tile (f32 VALU, proven); emits gT (bf16,
//      [c][j] transposed), slT2/srT2 (log2e-scaled) and per-head srmax ----
__launch_bounds__(256)
__global__ void k_gemm(const float* __restrict__ hmat, const float* __restrict__ W,
                       const float* __restrict__ aw,
                       short* __restrict__ gT, float* __restrict__ slT2,
                       float* __restrict__ srT2, uint32_t* __restrict__ srmax2){
  __shared__ float hsT[64][68];   // [k][row]
  __shared__ float wsT[64][68];   // [k][col]
  __shared__ float smax_l[16];
  int t  = threadIdx.x;
  int tx = t & 15, ty = t >> 4;
  int r0 = blockIdx.x * 64;
  int cb = blockIdx.y;            // head
  int c0 = cb * 64;
  float acc[4][4] = {};

  for (int k0 = 0; k0 < INF_; k0 += 64){
    int row = t >> 2, kc = (t & 3) * 16;   // transpose-on-load (h tile)
    #pragma unroll
    for (int u = 0; u < 4; u++){
      float4 v = *(const float4*)&hmat[(r0 + row)*INF_ + k0 + kc + 4*u];
      hsT[kc + 4*u + 0][row] = v.x;
      hsT[kc + 4*u + 1][row] = v.y;
      hsT[kc + 4*u + 2][row] = v.z;
      hsT[kc + 4*u + 3][row] = v.w;
    }
    #pragma unroll
    for (int u = 0; u < 4; u++){            // W[c][k] -> wsT[k][c]
      float4 v = *(const float4*)&W[(c0 + row)*INF_ + k0 + kc + 4*u];
      wsT[kc + 4*u + 0][row] = v.x;
      wsT[kc + 4*u + 1][row] = v.y;
      wsT[kc + 4*u + 2][row] = v.z;
      wsT[kc + 4*u + 3][row] = v.w;
    }
    __syncthreads();
    #pragma unroll 8
    for (int k = 0; k < 64; k++){
      float4 hv = *(const float4*)&hsT[k][ty*4];
      float4 wv = *(const float4*)&wsT[k][tx*4];
      float ha[4] = {hv.x, hv.y, hv.z, hv.w};
      float wa[4] = {wv.x, wv.y, wv.z, wv.w};
      #pragma unroll
      for (int a_ = 0; a_ < 4; a_++)
        #pragma unroll
        for (int b_ = 0; b_ < 4; b_++)
          acc[a_][b_] = fmaf(ha[a_], wa[b_], acc[a_][b_]);
    }
    __syncthreads();
  }

  // scores (log2e-scaled)
  float alv[4], arv[4];
  #pragma unroll
  for (int j = 0; j < 4; j++){ alv[j] = aw[tx*4 + j]; arv[j] = aw[64 + tx*4 + j]; }
  float rmax = -3.4e38f;
  #pragma unroll
  for (int qi = 0; qi < 4; qi++){
    int r = r0 + ty*4 + qi;
    float slp = 0.f, srp = 0.f;
    #pragma unroll
    for (int j = 0; j < 4; j++){
      slp = fmaf(acc[qi][j], alv[j], slp);
      srp = fmaf(acc[qi][j], arv[j], srp);
    }
    #pragma unroll
    for (int m = 1; m < 16; m <<= 1){
      slp += __shfl_xor(slp, m, 64);
      srp += __shfl_xor(srp, m, 64);
    }
    if (tx == 0){
      slT2[(size_t)cb*NN + r] = slp * L2E;
      srT2[(size_t)cb*NN + r] = srp * L2E;
      rmax = fmaxf(rmax, srp * L2E);
    }
  }
  if (tx == 0) smax_l[ty] = rmax;

  // transpose acc -> gT (bf16) via LDS reuse
  float* T = (float*)hsT;                    // [c][r] stride 65
  #pragma unroll
  for (int qi = 0; qi < 4; qi++)
    #pragma unroll
    for (int j = 0; j < 4; j++)
      T[(tx*4 + j)*65 + ty*4 + qi] = acc[qi][j];
  __syncthreads();
  if (t == 0){
    float m = smax_l[0];
    #pragma unroll
    for (int i = 1; i < 16; i++) m = fmaxf(m, smax_l[i]);
    atomicMax(srmax2 + cb, ford(m));
  }
  int c = t >> 2, rb = (t & 3) * 16;
  ushort u16[16];
  #pragma unroll
  for (int v = 0; v < 16; v++) u16[v] = bf16u(T[c*65 + rb + v]);
  *(uint4*)&gT[(size_t)(c0 + c)*NN + r0 + rb]     = *(uint4*)&u16[0];
  *(uint4*)&gT[(size_t)(c0 + c)*NN + r0 + rb + 8] = *(uint4*)&u16[8];
}

// ---- fused masked-softmax attention: r11 champion structure, B prefetch
//      deepened to 3 steps (static s%3 rotation), launch_bounds(256,3) ----
__launch_bounds__(256, 3)
__global__ void k_attn(const short* __restrict__ gT, const float* __restrict__ slT2,
                       const float* __restrict__ srT2, const uint32_t* __restrict__ srmax2,
                       const uint32_t* __restrict__ bm,
                       __hip_bfloat16* __restrict__ num_p, float* __restrict__ den_p){
  __shared__ uint32_t bmlds[32 * 18];   // [row][word] stride 18 -> conflict-free
  __shared__ float    srs[4][512];      // [head][j - jb], log2e-scaled
  int t  = threadIdx.x;
  int h  = t >> 6, l = t & 63;
  int lr = l & 15, lg = l >> 4;
  int i0 = blockIdx.x * BI;
  int jb = blockIdx.y * NJ;
  int js = blockIdx.y;

  // stage sr slice (wave h loads its head's 512 scores) + bitmask tile
  {
    int jj = l * 8;
    *(float4*)&srs[h][jj]     = *(const float4*)&srT2[(size_t)h*NN + jb + jj];
    *(float4*)&srs[h][jj + 4] = *(const float4*)&srT2[(size_t)h*NN + jb + jj + 4];
    int r = t >> 3, wd = (t & 7) * 2;
    uint2 v = *(const uint2*)&bm[(size_t)(i0 + r)*128 + (jb >> 5) + wd];
    bmlds[r*18 + wd]     = v.x;
    bmlds[r*18 + wd + 1] = v.y;
  }

  float srmaxh = funord(srmax2[h]);
  float d1[2], cc[2];
  #pragma unroll
  for (int m = 0; m < 2; m++){
    float slv = slT2[(size_t)h*NN + i0 + m*16 + lr];
    float xx  = slv + srmaxh;
    float msh = fmaxf(xx, NEG * xx);
    d1[m] = slv - msh;              // z = d1 + sr
    cc[m] = (NEG - 1.0f) * msh;     // neg branch: NEG*z + cc
  }
  __syncthreads();

  f32x4 acc[2][4] = {};
  f32x4 dacc[2]   = {};
  bf16x8 ones;
  #pragma unroll
  for (int q = 0; q < 8; q++) ones[q] = (short)0x3F80;

  const short* gTh = gT + (size_t)h*HID*NN;
  const short* bp[4];
  #pragma unroll
  for (int n = 0; n < 4; n++)
    bp[n] = gTh + (size_t)(n*16 + lr)*NN + jb + lg*8;

  bf16x8 Bb[3][4];
  #pragma unroll
  for (int n = 0; n < 4; n++){
    Bb[0][n] = *(const bf16x8*)(bp[n]);
    Bb[1][n] = *(const bf16x8*)(bp[n] + 32);
    Bb[2][n] = *(const bf16x8*)(bp[n] + 64);
  }

  // step-0 LDS operands
  float4 s0c = *(const float4*)&srs[h][lg*8];
  float4 s1c = *(const float4*)&srs[h][lg*8 + 4];
  uint32_t w0c = bmlds[lr*18];
  uint32_t w1c = bmlds[(16 + lr)*18];

  #pragma unroll
  for (int s = 0; s < 16; s++){
    // prefetch next step's LDS operands
    float4 s0n = s0c, s1n = s1c;
    uint32_t w0n = 0, w1n = 0;
    if (s < 15){
      s0n = *(const float4*)&srs[h][(s+1)*32 + lg*8];
      s1n = *(const float4*)&srs[h][(s+1)*32 + lg*8 + 4];
      w0n = bmlds[lr*18 + s + 1];
      w1n = bmlds[(16 + lr)*18 + s + 1];
    }
    float sr8[8] = {s0c.x, s0c.y, s0c.z, s0c.w, s1c.x, s1c.y, s1c.z, s1c.w};

    bf16x8 A[2];
    #pragma unroll
    for (int m = 0; m < 2; m++){
      uint32_t word = (m ? w1c : w0c) >> (lg*8);
      uint32_t pk[4];
      #pragma unroll
      for (int p = 0; p < 4; p++){
        float z0 = d1[m] + sr8[2*p];
        float z1 = d1[m] + sr8[2*p + 1];
        float v0 = __builtin_amdgcn_exp2f(fmaxf(z0, fmaf(NEG, z0, cc[m])));
        float v1 = __builtin_amdgcn_exp2f(fmaxf(z1, fmaf(NEG, z1, cc[m])));
        int m0 = (int)(word << (31 - 2*p)) >> 31;     // bit 2p   -> all-ones/zero
        int m1 = (int)(word << (30 - 2*p)) >> 31;     // bit 2p+1
        v0 = __uint_as_float(__float_as_uint(v0) & (uint32_t)m0);
        v1 = __uint_as_float(__float_as_uint(v1) & (uint32_t)m1);
        pk[p] = ((__float_as_uint(v0) + 0x8000u) >> 16) |
                ((__float_as_uint(v1) + 0x8000u) & 0xffff0000u);
      }
      A[m] = *(bf16x8*)pk;
    }

    __builtin_amdgcn_s_setprio(1);
    dacc[0] = __builtin_amdgcn_mfma_f32_16x16x32_bf16(A[0], ones, dacc[0], 0, 0, 0);
    #pragma unroll
    for (int n = 0; n < 4; n++)
      acc[0][n] = __builtin_amdgcn_mfma_f32_16x16x32_bf16(A[0], Bb[s % 3][n], acc[0][n], 0, 0, 0);
    dacc[1] = __builtin_amdgcn_mfma_f32_16x16x32_bf16(A[1], ones, dacc[1], 0, 0, 0);
    #pragma unroll
    for (int n = 0; n < 4; n++)
      acc[1][n] = __builtin_amdgcn_mfma_f32_16x16x32_bf16(A[1], Bb[s % 3][n], acc[1][n], 0, 0, 0);
    __builtin_amdgcn_s_setprio(0);

    if (s + 3 < 16){
      #pragma unroll
      for (int n = 0; n < 4; n++)
        Bb[s % 3][n] = *(const bf16x8*)(bp[n] + (s + 3)*32);
    }
    s0c = s0n; s1c = s1n; w0c = w0n; w1c = w1n;
  }

  // num partials (bf16): row = i0+m*16+lg*4+r, col = h*64+n*16+lr
  #pragma unroll
  for (int m = 0; m < 2; m++)
    #pragma unroll
    for (int n = 0; n < 4; n++)
      #pragma unroll
      for (int r = 0; r < 4; r++)
        num_p[((size_t)js*NN + i0 + m*16 + lg*4 + r)*OUTC + h*HID + n*16 + lr] =
            __float2bfloat16(acc[m][n][r]);

  // den partials from ones-MFMA: row m*16+lg*4+r value sits in dacc[m][r] (any lr)
  if (lr == 0)
    #pragma unroll
    for (int m = 0; m < 2; m++)
      #pragma unroll
      for (int r = 0; r < 4; r++)
        den_p[((size_t)js*4 + h)*NN + i0 + m*16 + lg*4 + r] = dacc[m][r];
}

// ---- combine partials: out = sum(num)/sum(den), 2 cols/thread ----
__global__ void k_comb(const __hip_bfloat16* __restrict__ num_p,
                       const float* __restrict__ den_p, float* __restrict__ out){
  int t  = threadIdx.x;
  int r  = blockIdx.x*2 + (t >> 7);
  int c2 = (t & 127) * 2;
  int h  = c2 >> 6;
  float s0 = 0.f, s1 = 0.f, d = 0.f;
  #pragma unroll
  for (int js = 0; js < JSPLIT; js++){
    uint32_t u = *(const uint32_t*)&num_p[((size_t)js*NN + r)*OUTC + c2];
    s0 += __uint_as_float(u << 16);
    s1 += __uint_as_float(u & 0xffff0000u);
  }
  #pragma unroll
  for (int js = 0; js < JSPLIT; js++)
    d += den_p[((size_t)js*4 + h)*NN + r];
  float inv = 1.0f / d;
  *(float2*)&out[(size_t)r*OUTC + c2] = make_float2(s0*inv, s1*inv);
}

extern "C" void kernel_launch(void* const* d_in, const int* in_sizes, int n_in,
                              void* d_out, int out_size, void* d_ws, size_t ws_size,
                              hipStream_t stream){
  const float* hmat = (const float*)d_in[0];
  const int*   adj  = (const int*)d_in[1];     // int32 layout confirmed in r1
  const float* W    = (const float*)d_in[2];
  const float* aw   = (const float*)d_in[3];
  float* out = (float*)d_out;
  char*  ws  = (char*)d_ws;

  // ws layout (bytes), total ~21.6 MB
  uint32_t* srmax2 = (uint32_t*)(ws);                      // 64 B
  float*    slT2   = (float*)(ws + 1024);                  // 64 KB
  float*    srT2   = (float*)(ws + 66560);                 // 64 KB
  short*    gT     = (short*)(ws + 132096);                // 2 MB   [256][4096] bf16
  float*    den_p  = (float*)(ws + 2229248);               // 512 KB [8][4][4096]
  __hip_bfloat16* num_p = (__hip_bfloat16*)(ws + 2753536); // 16.75 MB [8][4096][256]
  uint32_t* bmask  = (uint32_t*)(ws + 19530752);           // 2 MB   [4096][128] (byte-packed)

  hipMemsetAsync(ws, 0, 64, stream);   // srmax2 init
  hipLaunchKernelGGL(k_pack, dim3(NN/2), dim3(256), 0, stream, adj, (ushort*)bmask);
  hipLaunchKernelGGL(k_gemm, dim3(64, 4), dim3(256), 0, stream,
                     hmat, W, aw, gT, slT2, srT2, srmax2);
  hipLaunchKernelGGL(k_attn, dim3(NN/BI, JSPLIT), dim3(256), 0, stream,
                     gT, slT2, srT2, srmax2, bmask, num_p, den_p);
  hipLaunchKernelGGL(k_comb, dim3(NN/2), dim3(256), 0, stream, num_p, den_p, out);
}

// Round 15
// 68.514 us; speedup vs baseline: 1.5126x; 1.1410x over previous
//
#include <hip/hip_runtime.h>
#include <hip/hip_bf16.h>
#include <stdint.h>

#define NN    4096
#define INF_  256
#define HEADS 4
#define HID   64
#define OUTC  256
#define NEG   0.2f
#define L2E   1.44269504f

#define BI     32
#define JSPLIT 8
#define NJ     (NN / JSPLIT)

typedef short bf16x8 __attribute__((ext_vector_type(8)));
typedef float f32x4  __attribute__((ext_vector_type(4)));

// ---- float <-> order-preserving uint encoding (for atomicMax on f32) ----
__device__ __forceinline__ uint32_t ford(float x){
  uint32_t u = __float_as_uint(x);
  return (u & 0x80000000u) ? ~u : (u | 0x80000000u);
}
__device__ __forceinline__ float funord(uint32_t e){
  uint32_t u = (e & 0x80000000u) ? (e & 0x7fffffffu) : ~e;
  return __uint_as_float(u);
}
__device__ __forceinline__ ushort bf16u(float f){
  __hip_bfloat16 b = __float2bfloat16(f);
  return *reinterpret_cast<ushort*>(&b);
}

__device__ __forceinline__ uint32_t pack16(int4 v0, int4 v1, int4 v2, int4 v3){
  uint32_t b = 0;
  b |= (v0.x ? 0x0001u : 0u); b |= (v0.y ? 0x0002u : 0u);
  b |= (v0.z ? 0x0004u : 0u); b |= (v0.w ? 0x0008u : 0u);
  b |= (v1.x ? 0x0010u : 0u); b |= (v1.y ? 0x0020u : 0u);
  b |= (v1.z ? 0x0040u : 0u); b |= (v1.w ? 0x0080u : 0u);
  b |= (v2.x ? 0x0100u : 0u); b |= (v2.y ? 0x0200u : 0u);
  b |= (v2.z ? 0x0400u : 0u); b |= (v2.w ? 0x0800u : 0u);
  b |= (v3.x ? 0x1000u : 0u); b |= (v3.y ? 0x2000u : 0u);
  b |= (v3.z ? 0x4000u : 0u); b |= (v3.w ? 0x8000u : 0u);
  return b;
}

// ---- fused prep: blocks 0..255 = g-GEMM (r13 verbatim, dispatched first,
//      feeds attn's critical path); blocks 256..2303 = adjacency pack
//      (r13 verbatim, 2 rows/block, MLP=8). Independent work, concurrent. ----
__launch_bounds__(256)
__global__ void k_prep(const int* __restrict__ adj, const float* __restrict__ hmat,
                       const float* __restrict__ W, const float* __restrict__ aw,
                       ushort* __restrict__ bmb, short* __restrict__ gT,
                       float* __restrict__ slT2, float* __restrict__ srT2,
                       uint32_t* __restrict__ srmax2){
  __shared__ float hsT[64][68];   // [k][row]   (gemm role only)
  __shared__ float wsT[64][68];   // [k][col]
  __shared__ float smax_l[16];
  int bid = blockIdx.x;
  int t   = threadIdx.x;

  if (bid >= 256){
    // ---- pack role ----
    int row = (bid - 256) * 2;
    const int* p0 = adj + (size_t)row*NN + t*16;
    const int* p1 = p0 + NN;
    int4 a0 = *(const int4*)(p0);      int4 a1 = *(const int4*)(p0 + 4);
    int4 a2 = *(const int4*)(p0 + 8);  int4 a3 = *(const int4*)(p0 + 12);
    int4 b0 = *(const int4*)(p1);      int4 b1 = *(const int4*)(p1 + 4);
    int4 b2 = *(const int4*)(p1 + 8);  int4 b3 = *(const int4*)(p1 + 12);
    bmb[(size_t)row*256 + t]       = (ushort)pack16(a0, a1, a2, a3);
    bmb[(size_t)(row + 1)*256 + t] = (ushort)pack16(b0, b1, b2, b3);
    return;
  }

  // ---- gemm role (r13 k_gemm verbatim; bx = bid&63 row-tile, by = bid>>6 head) ----
  int tx = t & 15, ty = t >> 4;
  int r0 = (bid & 63) * 64;
  int cb = bid >> 6;              // head
  int c0 = cb * 64;
  float acc[4][4] = {};

  for (int k0 = 0; k0 < INF_; k0 += 64){
    int row = t >> 2, kc = (t & 3) * 16;   // transpose-on-load (h tile)
    #pragma unroll
    for (int u = 0; u < 4; u++){
      float4 v = *(const float4*)&hmat[(r0 + row)*INF_ + k0 + kc + 4*u];
      hsT[kc + 4*u + 0][row] = v.x;
      hsT[kc + 4*u + 1][row] = v.y;
      hsT[kc + 4*u + 2][row] = v.z;
      hsT[kc + 4*u + 3][row] = v.w;
    }
    #pragma unroll
    for (int u = 0; u < 4; u++){            // W[c][k] -> wsT[k][c]
      float4 v = *(const float4*)&W[(c0 + row)*INF_ + k0 + kc + 4*u];
      wsT[kc + 4*u + 0][row] = v.x;
      wsT[kc + 4*u + 1][row] = v.y;
      wsT[kc + 4*u + 2][row] = v.z;
      wsT[kc + 4*u + 3][row] = v.w;
    }
    __syncthreads();
    #pragma unroll 8
    for (int k = 0; k < 64; k++){
      float4 hv = *(const float4*)&hsT[k][ty*4];
      float4 wv = *(const float4*)&wsT[k][tx*4];
      float ha[4] = {hv.x, hv.y, hv.z, hv.w};
      float wa[4] = {wv.x, wv.y, wv.z, wv.w};
      #pragma unroll
      for (int a_ = 0; a_ < 4; a_++)
        #pragma unroll
        for (int b_ = 0; b_ < 4; b_++)
          acc[a_][b_] = fmaf(ha[a_], wa[b_], acc[a_][b_]);
    }
    __syncthreads();
  }

  // scores (log2e-scaled)
  float alv[4], arv[4];
  #pragma unroll
  for (int j = 0; j < 4; j++){ alv[j] = aw[tx*4 + j]; arv[j] = aw[64 + tx*4 + j]; }
  float rmax = -3.4e38f;
  #pragma unroll
  for (int qi = 0; qi < 4; qi++){
    int r = r0 + ty*4 + qi;
    float slp = 0.f, srp = 0.f;
    #pragma unroll
    for (int j = 0; j < 4; j++){
      slp = fmaf(acc[qi][j], alv[j], slp);
      srp = fmaf(acc[qi][j], arv[j], srp);
    }
    #pragma unroll
    for (int m = 1; m < 16; m <<= 1){
      slp += __shfl_xor(slp, m, 64);
      srp += __shfl_xor(srp, m, 64);
    }
    if (tx == 0){
      slT2[(size_t)cb*NN + r] = slp * L2E;
      srT2[(size_t)cb*NN + r] = srp * L2E;
      rmax = fmaxf(rmax, srp * L2E);
    }
  }
  if (tx == 0) smax_l[ty] = rmax;

  // transpose acc -> gT (bf16) via LDS reuse
  float* T = (float*)hsT;                    // [c][r] stride 65
  #pragma unroll
  for (int qi = 0; qi < 4; qi++)
    #pragma unroll
    for (int j = 0; j < 4; j++)
      T[(tx*4 + j)*65 + ty*4 + qi] = acc[qi][j];
  __syncthreads();
  if (t == 0){
    float m = smax_l[0];
    #pragma unroll
    for (int i = 1; i < 16; i++) m = fmaxf(m, smax_l[i]);
    atomicMax(srmax2 + cb, ford(m));
  }
  int c = t >> 2, rb = (t & 3) * 16;
  ushort u16[16];
  #pragma unroll
  for (int v = 0; v < 16; v++) u16[v] = bf16u(T[c*65 + rb + v]);
  *(uint4*)&gT[(size_t)(c0 + c)*NN + r0 + rb]     = *(uint4*)&u16[0];
  *(uint4*)&gT[(size_t)(c0 + c)*NN + r0 + rb + 8] = *(uint4*)&u16[8];
}

// ---- fused masked-softmax attention: r11 champion structure (BI=32 m=2,
//      LDS-staged bm+sr prefetched a step ahead, 2-deep reg-dbuf B, den via
//      ones-MFMA, sign-extend masking) + v_perm bf16-pair pack ----
__launch_bounds__(256, 4)
__global__ void k_attn(const short* __restrict__ gT, const float* __restrict__ slT2,
                       const float* __restrict__ srT2, const uint32_t* __restrict__ srmax2,
                       const uint32_t* __restrict__ bm,
                       __hip_bfloat16* __restrict__ num_p, float* __restrict__ den_p){
  __shared__ uint32_t bmlds[32 * 18];   // [row][word] stride 18 -> conflict-free
  __shared__ float    srs[4][512];      // [head][j - jb], log2e-scaled
  int t  = threadIdx.x;
  int h  = t >> 6, l = t & 63;
  int lr = l & 15, lg = l >> 4;
  int i0 = blockIdx.x * BI;
  int jb = blockIdx.y * NJ;
  int js = blockIdx.y;

  // stage sr slice (wave h loads its head's 512 scores) + bitmask tile
  {
    int jj = l * 8;
    *(float4*)&srs[h][jj]     = *(const float4*)&srT2[(size_t)h*NN + jb + jj];
    *(float4*)&srs[h][jj + 4] = *(const float4*)&srT2[(size_t)h*NN + jb + jj + 4];
    int r = t >> 3, wd = (t & 7) * 2;
    uint2 v = *(const uint2*)&bm[(size_t)(i0 + r)*128 + (jb >> 5) + wd];
    bmlds[r*18 + wd]     = v.x;
    bmlds[r*18 + wd + 1] = v.y;
  }

  float srmaxh = funord(srmax2[h]);
  float d1[2], cc[2];
  #pragma unroll
  for (int m = 0; m < 2; m++){
    float slv = slT2[(size_t)h*NN + i0 + m*16 + lr];
    float xx  = slv + srmaxh;
    float msh = fmaxf(xx, NEG * xx);
    d1[m] = slv - msh;              // z = d1 + sr
    cc[m] = (NEG - 1.0f) * msh;     // neg branch: NEG*z + cc
  }
  __syncthreads();

  f32x4 acc[2][4] = {};
  f32x4 dacc[2]   = {};
  bf16x8 ones;
  #pragma unroll
  for (int q = 0; q < 8; q++) ones[q] = (short)0x3F80;

  const short* gTh = gT + (size_t)h*HID*NN;
  const short* bp[4];
  #pragma unroll
  for (int n = 0; n < 4; n++)
    bp[n] = gTh + (size_t)(n*16 + lr)*NN + jb + lg*8;

  bf16x8 Bb[2][4];
  #pragma unroll
  for (int n = 0; n < 4; n++){
    Bb[0][n] = *(const bf16x8*)(bp[n]);
    Bb[1][n] = *(const bf16x8*)(bp[n] + 32);
  }

  // step-0 LDS operands
  float4 s0c = *(const float4*)&srs[h][lg*8];
  float4 s1c = *(const float4*)&srs[h][lg*8 + 4];
  uint32_t w0c = bmlds[lr*18];
  uint32_t w1c = bmlds[(16 + lr)*18];

  #pragma unroll
  for (int s = 0; s < 16; s++){
    // prefetch next step's LDS operands
    float4 s0n = s0c, s1n = s1c;
    uint32_t w0n = 0, w1n = 0;
    if (s < 15){
      s0n = *(const float4*)&srs[h][(s+1)*32 + lg*8];
      s1n = *(const float4*)&srs[h][(s+1)*32 + lg*8 + 4];
      w0n = bmlds[lr*18 + s + 1];
      w1n = bmlds[(16 + lr)*18 + s + 1];
    }
    float sr8[8] = {s0c.x, s0c.y, s0c.z, s0c.w, s1c.x, s1c.y, s1c.z, s1c.w};

    bf16x8 A[2];
    #pragma unroll
    for (int m = 0; m < 2; m++){
      uint32_t word = (m ? w1c : w0c) >> (lg*8);
      uint32_t pk[4];
      #pragma unroll
      for (int p = 0; p < 4; p++){
        float z0 = d1[m] + sr8[2*p];
        float z1 = d1[m] + sr8[2*p + 1];
        float v0 = __builtin_amdgcn_exp2f(fmaxf(z0, fmaf(NEG, z0, cc[m])));
        float v1 = __builtin_amdgcn_exp2f(fmaxf(z1, fmaf(NEG, z1, cc[m])));
        int m0 = (int)(word << (31 - 2*p)) >> 31;     // bit 2p   -> all-ones/zero
        int m1 = (int)(word << (30 - 2*p)) >> 31;     // bit 2p+1
        v0 = __uint_as_float(__float_as_uint(v0) & (uint32_t)m0);
        v1 = __uint_as_float(__float_as_uint(v1) & (uint32_t)m1);
        // round-to-nearest bf16 pair, packed with one v_perm_b32
        uint32_t u0 = __float_as_uint(v0) + 0x8000u;
        uint32_t u1 = __float_as_uint(v1) + 0x8000u;
        pk[p] = __builtin_amdgcn_perm(u1, u0, 0x07060302u);  // {u1.hi16, u0.hi16}
      }
      A[m] = *(bf16x8*)pk;
    }

    __builtin_amdgcn_s_setprio(1);
    dacc[0] = __builtin_amdgcn_mfma_f32_16x16x32_bf16(A[0], ones, dacc[0], 0, 0, 0);
    #pragma unroll
    for (int n = 0; n < 4; n++)
      acc[0][n] = __builtin_amdgcn_mfma_f32_16x16x32_bf16(A[0], Bb[s & 1][n], acc[0][n], 0, 0, 0);
    dacc[1] = __builtin_amdgcn_mfma_f32_16x16x32_bf16(A[1], ones, dacc[1], 0, 0, 0);
    #pragma unroll
    for (int n = 0; n < 4; n++)
      acc[1][n] = __builtin_amdgcn_mfma_f32_16x16x32_bf16(A[1], Bb[s & 1][n], acc[1][n], 0, 0, 0);
    __builtin_amdgcn_s_setprio(0);

    if (s + 2 < 16){
      #pragma unroll
      for (int n = 0; n < 4; n++)
        Bb[s & 1][n] = *(const bf16x8*)(bp[n] + (s + 2)*32);
    }
    s0c = s0n; s1c = s1n; w0c = w0n; w1c = w1n;
  }

  // num partials (bf16): row = i0+m*16+lg*4+r, col = h*64+n*16+lr
  #pragma unroll
  for (int m = 0; m < 2; m++)
    #pragma unroll
    for (int n = 0; n < 4; n++)
      #pragma unroll
      for (int r = 0; r < 4; r++)
        num_p[((size_t)js*NN + i0 + m*16 + lg*4 + r)*OUTC + h*HID + n*16 + lr] =
            __float2bfloat16(acc[m][n][r]);

  // den partials from ones-MFMA: row m*16+lg*4+r value sits in dacc[m][r] (any lr)
  if (lr == 0)
    #pragma unroll
    for (int m = 0; m < 2; m++)
      #pragma unroll
      for (int r = 0; r < 4; r++)
        den_p[((size_t)js*4 + h)*NN + i0 + m*16 + lg*4 + r] = dacc[m][r];
}

// ---- combine partials: out = sum(num)/sum(den), 2 cols/thread ----
__global__ void k_comb(const __hip_bfloat16* __restrict__ num_p,
                       const float* __restrict__ den_p, float* __restrict__ out){
  int t  = threadIdx.x;
  int r  = blockIdx.x*2 + (t >> 7);
  int c2 = (t & 127) * 2;
  int h  = c2 >> 6;
  float s0 = 0.f, s1 = 0.f, d = 0.f;
  #pragma unroll
  for (int js = 0; js < JSPLIT; js++){
    uint32_t u = *(const uint32_t*)&num_p[((size_t)js*NN + r)*OUTC + c2];
    s0 += __uint_as_float(u << 16);
    s1 += __uint_as_float(u & 0xffff0000u);
  }
  #pragma unroll
  for (int js = 0; js < JSPLIT; js++)
    d += den_p[((size_t)js*4 + h)*NN + r];
  float inv = 1.0f / d;
  *(float2*)&out[(size_t)r*OUTC + c2] = make_float2(s0*inv, s1*inv);
}

extern "C" void kernel_launch(void* const* d_in, const int* in_sizes, int n_in,
                              void* d_out, int out_size, void* d_ws, size_t ws_size,
                              hipStream_t stream){
  const float* hmat = (const float*)d_in[0];
  const int*   adj  = (const int*)d_in[1];     // int32 layout confirmed in r1
  const float* W    = (const float*)d_in[2];
  const float* aw   = (const float*)d_in[3];
  float* out = (float*)d_out;
  char*  ws  = (char*)d_ws;

  // ws layout (bytes), total ~21.6 MB
  uint32_t* srmax2 = (uint32_t*)(ws);                      // 64 B
  float*    slT2   = (float*)(ws + 1024);                  // 64 KB
  float*    srT2   = (float*)(ws + 66560);                 // 64 KB
  short*    gT     = (short*)(ws + 132096);                // 2 MB   [256][4096] bf16
  float*    den_p  = (float*)(ws + 2229248);               // 512 KB [8][4][4096]
  __hip_bfloat16* num_p = (__hip_bfloat16*)(ws + 2753536); // 16.75 MB [8][4096][256]
  uint32_t* bmask  = (uint32_t*)(ws + 19530752);           // 2 MB   [4096][128] (byte-packed)

  hipMemsetAsync(ws, 0, 64, stream);   // srmax2 init
  hipLaunchKernelGGL(k_prep, dim3(2304), dim3(256), 0, stream,
                     adj, hmat, W, aw, (ushort*)bmask, gT, slT2, srT2, srmax2);
  hipLaunchKernelGGL(k_attn, dim3(NN/BI, JSPLIT), dim3(256), 0, stream,
                     gT, slT2, srT2, srmax2, bmask, num_p, den_p);
  hipLaunchKernelGGL(k_comb, dim3(NN/2), dim3(256), 0, stream, num_p, den_p, out);
}